// Round 1
// baseline (338.829 us; speedup 1.0000x reference)
//
#include <hip/hip_runtime.h>
#include <math.h>

// Problem geometry
#define T_LEN   160000
#define NROW    128      // 64 rows of x then 64 rows of n
#define CHUNK   320      // L: serial steps per thread in big passes
#define NCHUNK  500      // C: chunks per row (CHUNK*NCHUNK == T_LEN)
#define PLEN    (CHUNK + 2)   // P[k] = p[k-1]; p[-1]=0, p[0]=1

#define A1_HP (-1.99599)
#define A2_HP (0.996)

__device__ __forceinline__ float clip1f(float v) { return fminf(fmaxf(v, -1.0f), 1.0f); }

// ---------------------------------------------------------------------------
// prep: homogeneous-response tables p for the 3 filters (hp, coef_x, coef_n)
// P[k] = p[k-1]:  P[0]=0, P[1]=1, P[k] = -a1*P[k-1] - a2*P[k-2]
// ---------------------------------------------------------------------------
__global__ void prep_kernel(const float* __restrict__ cx, const float* __restrict__ cn,
                            double* __restrict__ Pd) {
  int f = threadIdx.x;
  if (f >= 3) return;
  double a1, a2;
  if (f == 0) { a1 = A1_HP; a2 = A2_HP; }
  else { const float* c = (f == 1) ? cx : cn; a1 = (double)c[0]; a2 = (double)c[1]; }
  double* P = Pd + (size_t)f * PLEN;
  P[0] = 0.0; P[1] = 1.0;
  double pm1 = 0.0, p0 = 1.0;
  for (int k = 2; k < PLEN; ++k) {
    double pn = -a1 * p0 - a2 * pm1;
    P[k] = pn; pm1 = p0; p0 = pn;
  }
}

// ---------------------------------------------------------------------------
// Pass A1: stage-1 (fixed HP biquad) local IIR per (row, chunk), zero y-state,
// true x-history. Writes local y into d_out (in place), end state into e1.
// ---------------------------------------------------------------------------
__global__ __launch_bounds__(256) void pass_a1(const float* __restrict__ x,
                                               const float* __restrict__ nn,
                                               float* __restrict__ out,
                                               double* __restrict__ e1) {
  int g = blockIdx.x * blockDim.x + threadIdx.x;
  if (g >= NROW * NCHUNK) return;
  int row = g / NCHUNK, c = g % NCHUNK;
  const float* src = (row < 64) ? (x + (size_t)row * T_LEN)
                                : (nn + (size_t)(row - 64) * T_LEN);
  const float* xp = src + (size_t)c * CHUNK;
  float* op = out + (size_t)row * T_LEN + (size_t)c * CHUNK;
  const double a1 = A1_HP, a2 = A2_HP;
  double x1 = 0.0, x2 = 0.0;
  if (c > 0) { x1 = (double)xp[-1]; x2 = (double)xp[-2]; }
  double y1 = 0.0, y2 = 0.0;
  for (int j = 0; j < CHUNK; j += 4) {
    float4 xv = *reinterpret_cast<const float4*>(xp + j);
    float4 ov;
#define A1STEP(XF, OF) { double xt = (double)(XF); \
    double y = xt - 2.0 * x1 + x2 - a1 * y1 - a2 * y2; \
    OF = (float)y; x2 = x1; x1 = xt; y2 = y1; y1 = y; }
    A1STEP(xv.x, ov.x) A1STEP(xv.y, ov.y) A1STEP(xv.z, ov.z) A1STEP(xv.w, ov.w)
#undef A1STEP
    *reinterpret_cast<float4*>(op + j) = ov;
  }
  size_t si = (size_t)g * 2;
  e1[si] = y1; e1[si + 1] = y2;
}

// ---------------------------------------------------------------------------
// combine: per-row sequential scan over chunks:  s_{c+1} = M s_c + e_c
// M = [[p[L], -a2 p[L-1]], [p[L-1], -a2 p[L-2]]]  (A^L via p-table)
// stage==1: HP filter for all rows.  stage==2: per-row coef_x / coef_n.
// ---------------------------------------------------------------------------
__global__ void combine_kernel(const double* __restrict__ Pd, const float* __restrict__ cx,
                               const float* __restrict__ cn, const double* __restrict__ e,
                               double* __restrict__ s, int stage) {
  int row = threadIdx.x;
  if (row >= NROW) return;
  const double* P; double a2;
  if (stage == 1) { P = Pd; a2 = A2_HP; }
  else { P = Pd + (size_t)((row < 64) ? 1 : 2) * PLEN;
         a2 = (double)((row < 64 ? cx : cn)[1]); }
  const double m00 = P[CHUNK + 1], m01 = -a2 * P[CHUNK];
  const double m10 = P[CHUNK],     m11 = -a2 * P[CHUNK - 1];
  double s1v = 0.0, s2v = 0.0;
  const double2* ep = reinterpret_cast<const double2*>(e) + (size_t)row * NCHUNK;
  double2* sp = reinterpret_cast<double2*>(s) + (size_t)row * NCHUNK;
  for (int c0 = 0; c0 < NCHUNK; c0 += 4) {
    double2 E0 = ep[c0], E1 = ep[c0 + 1], E2 = ep[c0 + 2], E3 = ep[c0 + 3];
    double2 S;
#define CSTEP(EE) { S.x = s1v; S.y = s2v; \
    double n1 = m00 * s1v + m01 * s2v + (EE).x; \
    double n2 = m10 * s1v + m11 * s2v + (EE).y; \
    s1v = n1; s2v = n2; }
    CSTEP(E0) sp[c0] = S;
    CSTEP(E1) sp[c0 + 1] = S;
    CSTEP(E2) sp[c0 + 2] = S;
    CSTEP(E3) sp[c0 + 3] = S;
#undef CSTEP
  }
}

// ---------------------------------------------------------------------------
// Pass A2: stage-1 correction + clip, then stage-2 local IIR (zero y-state,
// x-history = clip of exact stage-1 boundary states). In place on d_out.
// ---------------------------------------------------------------------------
__global__ __launch_bounds__(256) void pass_a2(float* __restrict__ out,
                                               const double* __restrict__ Pd,
                                               const double* __restrict__ s1,
                                               double* __restrict__ e2,
                                               const float* __restrict__ cx,
                                               const float* __restrict__ cn) {
  int g = blockIdx.x * blockDim.x + threadIdx.x;
  if (g >= NROW * NCHUNK) return;
  int row = g / NCHUNK, c = g % NCHUNK;
  const float* cf = (row < 64) ? cx : cn;
  const float A1c = cf[0], A2c = cf[1], B1c = cf[2], B2c = cf[3];
  size_t si = (size_t)g * 2;
  const double s1v = s1[si], s2v = s1[si + 1];
  float* op = out + (size_t)row * T_LEN + (size_t)c * CHUNK;
  // stage-2 x-history = clipped exact stage-1 boundary outputs (0 for c==0,
  // since stored start state is (0,0) there).
  float v1 = clip1f((float)s1v), v2 = clip1f((float)s2v);
  float z1 = 0.0f, z2 = 0.0f;
  const double a2 = A2_HP;
  for (int j = 0; j < CHUNK; j += 4) {
    float4 yv = *reinterpret_cast<const float4*>(op + j);
    float4 ov;
    double p1 = Pd[j + 1], p2v = Pd[j + 2], p3 = Pd[j + 3], p4 = Pd[j + 4], p5 = Pd[j + 5];
#define A2STEP(YF, OF, PJ1, PJ2) { \
    double corr = (PJ2) * s1v - a2 * (PJ1) * s2v; \
    float v = clip1f((float)((double)(YF) + corr)); \
    float ya = v + B1c * v1 + B2c * v2 - A1c * z1 - A2c * z2; \
    OF = ya; v2 = v1; v1 = v; z2 = z1; z1 = ya; }
    A2STEP(yv.x, ov.x, p1, p2v) A2STEP(yv.y, ov.y, p2v, p3)
    A2STEP(yv.z, ov.z, p3, p4)  A2STEP(yv.w, ov.w, p4, p5)
#undef A2STEP
    *reinterpret_cast<float4*>(op + j) = ov;
  }
  e2[si] = (double)z1; e2[si + 1] = (double)z2;
}

// ---------------------------------------------------------------------------
// Pass B2: stage-2 correction + final clip, in place on d_out.
// ---------------------------------------------------------------------------
__global__ __launch_bounds__(256) void pass_b2(float* __restrict__ out,
                                               const double* __restrict__ Pd,
                                               const double* __restrict__ s2,
                                               const float* __restrict__ cx,
                                               const float* __restrict__ cn) {
  int g = blockIdx.x * blockDim.x + threadIdx.x;
  if (g >= NROW * NCHUNK) return;
  int row = g / NCHUNK, c = g % NCHUNK;
  const double* P = Pd + (size_t)((row < 64) ? 1 : 2) * PLEN;
  const double A2c = (double)((row < 64 ? cx : cn)[1]);
  size_t si = (size_t)g * 2;
  const double s1v = s2[si], s2v = s2[si + 1];
  float* op = out + (size_t)row * T_LEN + (size_t)c * CHUNK;
  for (int j = 0; j < CHUNK; j += 4) {
    float4 yv = *reinterpret_cast<const float4*>(op + j);
    float4 ov;
    double p1 = P[j + 1], p2v = P[j + 2], p3 = P[j + 3], p4 = P[j + 4], p5 = P[j + 5];
#define B2STEP(YF, OF, PJ1, PJ2) \
    OF = clip1f((float)((double)(YF) + (PJ2) * s1v - A2c * (PJ1) * s2v));
    B2STEP(yv.x, ov.x, p1, p2v) B2STEP(yv.y, ov.y, p2v, p3)
    B2STEP(yv.z, ov.z, p3, p4)  B2STEP(yv.w, ov.w, p4, p5)
#undef B2STEP
    *reinterpret_cast<float4*>(op + j) = ov;
  }
}

// ---------------------------------------------------------------------------
extern "C" void kernel_launch(void* const* d_in, const int* in_sizes, int n_in,
                              void* d_out, int out_size, void* d_ws, size_t ws_size,
                              hipStream_t stream) {
  const float* x  = (const float*)d_in[0];   // (64, 160000)
  const float* nn = (const float*)d_in[1];   // (64, 160000)
  const float* cx = (const float*)d_in[2];   // (4,) a1,a2,b1,b2
  const float* cn = (const float*)d_in[3];   // (4,)
  float* out = (float*)d_out;                // (128, 160000) flat

  // workspace layout (doubles): P[3][PLEN], e1, s1, e2, s2 each [NROW*NCHUNK*2]
  double* Pd = (double*)d_ws;
  double* e1 = Pd + 3 * PLEN;
  double* s1 = e1 + (size_t)NROW * NCHUNK * 2;
  double* e2 = s1 + (size_t)NROW * NCHUNK * 2;
  double* s2 = e2 + (size_t)NROW * NCHUNK * 2;
  // total: (3*322 + 4*128000) * 8 B ~= 4.1 MB

  const int total = NROW * NCHUNK;         // 64000
  const int blk = 256;
  const int nb = (total + blk - 1) / blk;  // 250

  prep_kernel<<<1, 64, 0, stream>>>(cx, cn, Pd);
  pass_a1<<<nb, blk, 0, stream>>>(x, nn, out, e1);
  combine_kernel<<<1, 128, 0, stream>>>(Pd, cx, cn, e1, s1, 1);
  pass_a2<<<nb, blk, 0, stream>>>(out, Pd, s1, e2, cx, cn);
  combine_kernel<<<1, 128, 0, stream>>>(Pd, cx, cn, e2, s2, 2);
  pass_b2<<<nb, blk, 0, stream>>>(out, Pd, s2, cx, cn);
}

// Round 2
// 120.205 us; speedup vs baseline: 2.8188x; 2.8188x over previous
//
#include <hip/hip_runtime.h>
#include <math.h>

// Problem geometry
#define T_LEN   160000
#define NROW    128      // 64 rows of x then 64 rows of n
#define CHUNK   320      // L: serial steps per thread in big passes
#define NCHUNK  500      // C: chunks per row (CHUNK*NCHUNK == T_LEN)
#define PLEN    (CHUNK + 2)   // P[k] = p[k-1]; p[-1]=0, p[0]=1
#define CUT     96       // stage-2 correction horizon (pole^96 ~ 1e-8)

#define A1_HP (-1.99599)
#define A2_HP (0.996)

__device__ __forceinline__ float clip1f(float v) { return fminf(fmaxf(v, -1.0f), 1.0f); }

// ---------------------------------------------------------------------------
// prep: homogeneous-response tables p for the 3 filters (hp, coef_x, coef_n)
// P[k] = p[k-1]:  P[0]=0, P[1]=1, P[k] = -a1*P[k-1] - a2*P[k-2]
// ---------------------------------------------------------------------------
__global__ void prep_kernel(const float* __restrict__ cx, const float* __restrict__ cn,
                            double* __restrict__ Pd) {
  int f = threadIdx.x;
  if (f >= 3) return;
  double a1, a2;
  if (f == 0) { a1 = A1_HP; a2 = A2_HP; }
  else { const float* c = (f == 1) ? cx : cn; a1 = (double)c[0]; a2 = (double)c[1]; }
  double* P = Pd + (size_t)f * PLEN;
  P[0] = 0.0; P[1] = 1.0;
  double pm1 = 0.0, p0 = 1.0;
  for (int k = 2; k < PLEN; ++k) {
    double pn = -a1 * p0 - a2 * pm1;
    P[k] = pn; pm1 = p0; p0 = pn;
  }
}

// ---------------------------------------------------------------------------
// Pass A1: stage-1 (fixed HP biquad) local IIR per (row, chunk), zero y-state,
// true x-history. Writes local y into d_out (in place), end state into e1.
// ---------------------------------------------------------------------------
__global__ __launch_bounds__(256) void pass_a1(const float* __restrict__ x,
                                               const float* __restrict__ nn,
                                               float* __restrict__ out,
                                               double* __restrict__ e1) {
  int g = blockIdx.x * blockDim.x + threadIdx.x;
  if (g >= NROW * NCHUNK) return;
  int row = g / NCHUNK, c = g % NCHUNK;
  const float* src = (row < 64) ? (x + (size_t)row * T_LEN)
                                : (nn + (size_t)(row - 64) * T_LEN);
  const float* xp = src + (size_t)c * CHUNK;
  float* op = out + (size_t)row * T_LEN + (size_t)c * CHUNK;
  const double a1 = A1_HP, a2 = A2_HP;
  double x1 = 0.0, x2 = 0.0;
  if (c > 0) { x1 = (double)xp[-1]; x2 = (double)xp[-2]; }
  double y1 = 0.0, y2 = 0.0;
  for (int j = 0; j < CHUNK; j += 4) {
    float4 xv = *reinterpret_cast<const float4*>(xp + j);
    float4 ov;
#define A1STEP(XF, OF) { double xt = (double)(XF); \
    double y = xt - 2.0 * x1 + x2 - a1 * y1 - a2 * y2; \
    OF = (float)y; x2 = x1; x1 = xt; y2 = y1; y1 = y; }
    A1STEP(xv.x, ov.x) A1STEP(xv.y, ov.y) A1STEP(xv.z, ov.z) A1STEP(xv.w, ov.w)
#undef A1STEP
    *reinterpret_cast<float4*>(op + j) = ov;
  }
  size_t si = (size_t)g * 2;
  e1[si] = y1; e1[si + 1] = y2;
}

// ---------------------------------------------------------------------------
// scan1: wave-parallel per-row combine for stage 1 (constant matrix M).
// One wave (64 lanes) per row; lane l owns 8 consecutive chunks.
// f_l = sum_j M^{7-j} e_{8l+j}; Kogge-Stone over lanes with B=M^8 powers;
// then re-emit chunk-start states s[c].
// ---------------------------------------------------------------------------
__global__ __launch_bounds__(256) void scan1_kernel(const double* __restrict__ Pd,
                                                    const double* __restrict__ e,
                                                    double* __restrict__ s) {
  int tid = blockIdx.x * blockDim.x + threadIdx.x;
  int row = tid >> 6;
  int lane = tid & 63;
  if (row >= NROW) return;
  const double a2 = A2_HP;
  // M = A_hp^CHUNK from the P table
  const double m00 = Pd[CHUNK + 1], m01 = -a2 * Pd[CHUNK];
  const double m10 = Pd[CHUNK],     m11 = -a2 * Pd[CHUNK - 1];
  const double2* ep = reinterpret_cast<const double2*>(e) + (size_t)row * NCHUNK;
  int base = lane * 8;
  double2 ev[8];
#pragma unroll
  for (int j = 0; j < 8; ++j) {
    int c = base + j;
    ev[j] = (c < NCHUNK) ? ep[c] : make_double2(0.0, 0.0);
  }
  // local composition f = sum M^{7-j} e_j
  double f1 = 0.0, f2 = 0.0;
#pragma unroll
  for (int j = 0; j < 8; ++j) {
    double n1 = m00 * f1 + m01 * f2 + ev[j].x;
    double n2 = m10 * f1 + m11 * f2 + ev[j].y;
    f1 = n1; f2 = n2;
  }
  // B = M^8 (3 squarings)
  double b00 = m00, b01 = m01, b10 = m10, b11 = m11;
#pragma unroll
  for (int k = 0; k < 3; ++k) {
    double t00 = b00 * b00 + b01 * b10, t01 = b00 * b01 + b01 * b11;
    double t10 = b10 * b00 + b11 * b10, t11 = b10 * b01 + b11 * b11;
    b00 = t00; b01 = t01; b10 = t10; b11 = t11;
  }
  // Kogge-Stone inclusive scan: v_l += B^off * v_{l-off}; B squares each step
  double v1 = f1, v2 = f2;
#pragma unroll
  for (int off = 1; off < 64; off <<= 1) {
    double u1 = __shfl_up(v1, off);
    double u2 = __shfl_up(v2, off);
    if (lane >= off) {
      v1 += b00 * u1 + b01 * u2;
      v2 += b10 * u1 + b11 * u2;
    }
    double t00 = b00 * b00 + b01 * b10, t01 = b00 * b01 + b01 * b11;
    double t10 = b10 * b00 + b11 * b10, t11 = b10 * b01 + b11 * b11;
    b00 = t00; b01 = t01; b10 = t10; b11 = t11;
  }
  // exclusive across lanes
  double g1 = __shfl_up(v1, 1);
  double g2 = __shfl_up(v2, 1);
  if (lane == 0) { g1 = 0.0; g2 = 0.0; }
  // reconstruct chunk-start states
  double2* sp = reinterpret_cast<double2*>(s) + (size_t)row * NCHUNK;
  double s1v = g1, s2v = g2;
#pragma unroll
  for (int j = 0; j < 8; ++j) {
    int c = base + j;
    if (c < NCHUNK) sp[c] = make_double2(s1v, s2v);
    double n1 = m00 * s1v + m01 * s2v + ev[j].x;
    double n2 = m10 * s1v + m11 * s2v + ev[j].y;
    s1v = n1; s2v = n2;
  }
}

// ---------------------------------------------------------------------------
// Pass A2: stage-1 correction + clip, then stage-2 local IIR (zero y-state,
// x-history = clip of exact stage-1 boundary states). In place on d_out.
// For j >= CUT the stage-2 correction is < 1e-5, so write the FINAL clipped
// value; pass_b2 then only touches j < CUT.
// ---------------------------------------------------------------------------
__global__ __launch_bounds__(256) void pass_a2(float* __restrict__ out,
                                               const double* __restrict__ Pd,
                                               const double* __restrict__ s1,
                                               double* __restrict__ e2,
                                               const float* __restrict__ cx,
                                               const float* __restrict__ cn) {
  int g = blockIdx.x * blockDim.x + threadIdx.x;
  if (g >= NROW * NCHUNK) return;
  int row = g / NCHUNK, c = g % NCHUNK;
  const float* cf = (row < 64) ? cx : cn;
  const float A1c = cf[0], A2c = cf[1], B1c = cf[2], B2c = cf[3];
  size_t si = (size_t)g * 2;
  const double s1v = s1[si], s2v = s1[si + 1];
  float* op = out + (size_t)row * T_LEN + (size_t)c * CHUNK;
  float v1 = clip1f((float)s1v), v2 = clip1f((float)s2v);
  float z1 = 0.0f, z2 = 0.0f;
  const double a2 = A2_HP;
#define A2STEP(YF, OF, PJ1, PJ2, DOCLIP) { \
    double corr = (PJ2) * s1v - a2 * (PJ1) * s2v; \
    float v = clip1f((float)((double)(YF) + corr)); \
    float ya = v + B1c * v1 + B2c * v2 - A1c * z1 - A2c * z2; \
    OF = (DOCLIP) ? clip1f(ya) : ya; v2 = v1; v1 = v; z2 = z1; z1 = ya; }
  for (int j = 0; j < CUT; j += 4) {
    float4 yv = *reinterpret_cast<const float4*>(op + j);
    float4 ov;
    double p1 = Pd[j + 1], p2v = Pd[j + 2], p3 = Pd[j + 3], p4 = Pd[j + 4], p5 = Pd[j + 5];
    A2STEP(yv.x, ov.x, p1, p2v, 0) A2STEP(yv.y, ov.y, p2v, p3, 0)
    A2STEP(yv.z, ov.z, p3, p4, 0)  A2STEP(yv.w, ov.w, p4, p5, 0)
    *reinterpret_cast<float4*>(op + j) = ov;
  }
  for (int j = CUT; j < CHUNK; j += 4) {
    float4 yv = *reinterpret_cast<const float4*>(op + j);
    float4 ov;
    double p1 = Pd[j + 1], p2v = Pd[j + 2], p3 = Pd[j + 3], p4 = Pd[j + 4], p5 = Pd[j + 5];
    A2STEP(yv.x, ov.x, p1, p2v, 1) A2STEP(yv.y, ov.y, p2v, p3, 1)
    A2STEP(yv.z, ov.z, p3, p4, 1)  A2STEP(yv.w, ov.w, p4, p5, 1)
    *reinterpret_cast<float4*>(op + j) = ov;
  }
#undef A2STEP
  e2[si] = (double)z1; e2[si + 1] = (double)z2;
}

// ---------------------------------------------------------------------------
// Pass B2: stage-2 correction + final clip on the first CUT samples per chunk.
// Stage-2 transition matrix over a chunk is ~0 (poles^320 ~ 1e-26), so the
// chunk-start state is exactly e2 of the previous chunk — no combine needed.
// ---------------------------------------------------------------------------
__global__ __launch_bounds__(256) void pass_b2(float* __restrict__ out,
                                               const double* __restrict__ Pd,
                                               const double* __restrict__ e2,
                                               const float* __restrict__ cx,
                                               const float* __restrict__ cn) {
  int g = blockIdx.x * blockDim.x + threadIdx.x;
  if (g >= NROW * NCHUNK) return;
  int row = g / NCHUNK, c = g % NCHUNK;
  const double* P = Pd + (size_t)((row < 64) ? 1 : 2) * PLEN;
  const double A2c = (double)((row < 64 ? cx : cn)[1]);
  size_t si = (size_t)g * 2;
  double s1v = 0.0, s2v = 0.0;
  if (c > 0) { s1v = e2[si - 2]; s2v = e2[si - 1]; }
  float* op = out + (size_t)row * T_LEN + (size_t)c * CHUNK;
  for (int j = 0; j < CUT; j += 4) {
    float4 yv = *reinterpret_cast<const float4*>(op + j);
    float4 ov;
    double p1 = P[j + 1], p2v = P[j + 2], p3 = P[j + 3], p4 = P[j + 4], p5 = P[j + 5];
#define B2STEP(YF, OF, PJ1, PJ2) \
    OF = clip1f((float)((double)(YF) + (PJ2) * s1v - A2c * (PJ1) * s2v));
    B2STEP(yv.x, ov.x, p1, p2v) B2STEP(yv.y, ov.y, p2v, p3)
    B2STEP(yv.z, ov.z, p3, p4)  B2STEP(yv.w, ov.w, p4, p5)
#undef B2STEP
    *reinterpret_cast<float4*>(op + j) = ov;
  }
}

// ---------------------------------------------------------------------------
extern "C" void kernel_launch(void* const* d_in, const int* in_sizes, int n_in,
                              void* d_out, int out_size, void* d_ws, size_t ws_size,
                              hipStream_t stream) {
  const float* x  = (const float*)d_in[0];   // (64, 160000)
  const float* nn = (const float*)d_in[1];   // (64, 160000)
  const float* cx = (const float*)d_in[2];   // (4,) a1,a2,b1,b2
  const float* cn = (const float*)d_in[3];   // (4,)
  float* out = (float*)d_out;                // (128, 160000) flat

  // workspace layout (doubles): P[3][PLEN], e1, s1, e2 each [NROW*NCHUNK*2]
  double* Pd = (double*)d_ws;
  double* e1 = Pd + 3 * PLEN;
  double* s1 = e1 + (size_t)NROW * NCHUNK * 2;
  double* e2 = s1 + (size_t)NROW * NCHUNK * 2;

  const int total = NROW * NCHUNK;         // 64000
  const int blk = 256;
  const int nb = (total + blk - 1) / blk;  // 250

  prep_kernel<<<1, 64, 0, stream>>>(cx, cn, Pd);
  pass_a1<<<nb, blk, 0, stream>>>(x, nn, out, e1);
  scan1_kernel<<<32, 256, 0, stream>>>(Pd, e1, s1);   // 128 rows x 1 wave
  pass_a2<<<nb, blk, 0, stream>>>(out, Pd, s1, e2, cx, cn);
  pass_b2<<<nb, blk, 0, stream>>>(out, Pd, e2, cx, cn);
}